// Round 3
// baseline (281.700 us; speedup 1.0000x reference)
//
#include <hip/hip_runtime.h>
#include <math.h>

#define D2R      0.017453292519943295f
#define TWO_R    7917.6f                 /* 2 * 3958.8 miles */
#define TAU_LN2  0.17328679513998632f    /* tau * ln2  (for M - tau*ln(S) via log2) */
#define K_EXP2   5.770780163555854f      /* (1/tau) * log2(e) */
#define PIO2     1.5707963267948966f
#define MBIG     1.0e30f
#define DMASK    2.0e30f

// A&S 4.4.46: asin(x) = pi/2 - sqrt(1-x)*poly(x), x in [0,1], |err| <= 2e-8
__device__ __forceinline__ float asin_poly(float x) {
  float p = fmaf(x, -0.0012624911f, 0.0066700901f);
  p = fmaf(x, p, -0.0170881256f);
  p = fmaf(x, p,  0.0308918810f);
  p = fmaf(x, p, -0.0501743046f);
  p = fmaf(x, p,  0.0889789874f);
  p = fmaf(x, p, -0.2145988016f);
  p = fmaf(x, p,  1.5707963050f);
  float w = sqrtf(1.0f - x);
  return fmaf(-w, p, PIO2);
}

// ---------------- kernel 1: per-candidate trig precompute ----------------
// bin_coords flat (NBINS*M, 2) = [lon, lat] degrees.
// Store {0.5*lat_rad, 0.5*lon_rad, cos(lat_rad), 0} so the inner sin needs no *0.5.
__global__ __launch_bounds__(256) void prep_cand(
    const float2* __restrict__ bc, float4* __restrict__ ct, int total) {
  int i = blockIdx.x * 256 + threadIdx.x;
  if (i < total) {
    float2 ll  = bc[i];
    float latr = ll.y * D2R;
    float lonr = ll.x * D2R;
    ct[i] = make_float4(0.5f * latr, 0.5f * lonr, __cosf(latr), 0.0f);
  }
}

// ---------------- kernel 2: fused haversine + online logsumexp ----------------
// One block (256 threads) per prediction; ITERS candidates/thread, fully
// streaming: no distance array, no scratch. Online state (m, s):
//   s = sum exp2(K*(m - d)) over seen candidates, m = running min dist.
// Masked slots: d = DMASK(2e30) with m0 = MBIG(1e30) -> both exp2 args <= 0,
// contribution exactly 0, no predication of the state update needed.
template <int ITERS>
__global__ __launch_bounds__(256) void lse_kernel(
    const float2* __restrict__ preds,
    const float4* __restrict__ ct,
    const int*    __restrict__ xv,
    const int*    __restrict__ bin_counts,
    float* __restrict__ accF, int* __restrict__ accI, int M) {
  const int b   = blockIdx.x;
  const int tid = threadIdx.x;

  const int bin = xv[3 * b] * 25 + xv[3 * b + 1] * 5 + xv[3 * b + 2];
  const int cnt = bin_counts[bin];

  const float2 p    = preds[b];          // {lon, lat} degrees
  const float lat1  = p.y * D2R;
  const float lat1h = 0.5f * lat1;
  const float lon1h = 0.5f * (p.x * D2R);
  const float cl1   = __cosf(lat1);

  const float4* __restrict__ cb = ct + (size_t)bin * (size_t)M;

  float m = MBIG, s = 0.0f;
#pragma unroll
  for (int r = 0; r < ITERS; ++r) {
    const int idx = tid + r * 256;
    float4 c = cb[idx];                  // UNCONDITIONAL -> hoistable/pipelined
    float sd = __sinf(c.x - lat1h);      // sin(dlat/2)
    float sn = __sinf(c.y - lon1h);      // sin(dlon/2)
    float a  = fmaf(sd, sd, (cl1 * c.z) * (sn * sn));
    a = fminf(fmaxf(a, 0.0f), 1.0f);
    float d  = TWO_R * asin_poly(sqrtf(a));
    d = (idx < cnt) ? d : DMASK;
    // branchless online LSE update (2x exp2; one arg is 0 in the common case)
    float mn = fminf(m, d);
    s = fmaf(s, exp2f((mn - m) * K_EXP2), exp2f((mn - d) * K_EXP2));
    m = mn;
  }

  // ---- wave-level (m,s) merge ----
#pragma unroll
  for (int o = 32; o; o >>= 1) {
    float mo = __shfl_xor(m, o);
    float so = __shfl_xor(s, o);
    float mn = fminf(m, mo);
    s = fmaf(s, exp2f((mn - m) * K_EXP2), so * exp2f((mn - mo) * K_EXP2));
    m = mn;
  }

  // ---- cross-wave merge via LDS ----
  __shared__ float redm[4];
  __shared__ float reds[4];
  const int wave = tid >> 6;
  if ((tid & 63) == 0) { redm[wave] = m; reds[wave] = s; }
  __syncthreads();

  if (tid == 0 && cnt > 0) {
    float M4 = fminf(fminf(redm[0], redm[1]), fminf(redm[2], redm[3]));
    float S  = reds[0] * exp2f((M4 - redm[0]) * K_EXP2)
             + reds[1] * exp2f((M4 - redm[1]) * K_EXP2)
             + reds[2] * exp2f((M4 - redm[2]) * K_EXP2)
             + reds[3] * exp2f((M4 - redm[3]) * K_EXP2);
    float soft = M4 - TAU_LN2 * __log2f(S);   // = -tau * logsumexp(-d/tau)
    atomicAdd(accF, soft);
    atomicAdd(accI, 1);
  }
}

// ---------------- kernel 3: finalize ----------------
__global__ void fin_kernel(const float* __restrict__ accF,
                           const int* __restrict__ accI,
                           float* __restrict__ out) {
  int nv = *accI;
  if (nv < 1) nv = 1;
  out[0] = accF[0] / (float)nv;
}

extern "C" void kernel_launch(void* const* d_in, const int* in_sizes, int n_in,
                              void* d_out, int out_size, void* d_ws, size_t ws_size,
                              hipStream_t stream) {
  const float2* preds      = (const float2*)d_in[0];  // (B,2) [lon,lat]
  const float2* bin_coords = (const float2*)d_in[1];  // (125,M,2) [lon,lat]
  const int*    x_vals     = (const int*)d_in[2];     // (B,3)
  const int*    bin_counts = (const int*)d_in[3];     // (125,)
  float*        out        = (float*)d_out;

  const int B     = in_sizes[0] / 2;
  const int total = in_sizes[1] / 2;                  // NBINS * M
  const int NBINS = 125;
  const int M     = total / NBINS;                    // 4096

  float*  accF = (float*)d_ws;
  int*    accI = (int*)((char*)d_ws + 4);
  float4* ct   = (float4*)((char*)d_ws + 16);

  hipMemsetAsync(d_ws, 0, 16, stream);

  prep_cand<<<(total + 255) / 256, 256, 0, stream>>>(bin_coords, ct, total);

  lse_kernel<16><<<B, 256, 0, stream>>>(preds, ct, x_vals, bin_counts,
                                        accF, accI, M);

  fin_kernel<<<1, 1, 0, stream>>>(accF, accI, out);
}